// Round 4
// baseline (1636.168 us; speedup 1.0000x reference)
//
#include <hip/hip_runtime.h>

// ---------------------------------------------------------------------------
// StyleDecorator, round 4: bf16x3 (6-term) MFMA everywhere.
//  - NS back to LDS-tiled gemm_sp (round-3 register-direct regressed).
//  - Power-iteration lambda_max estimate -> tighter NS scaling -> 8 iters.
//  - NS products are symmetric: compute 36/64 triangle blocks + mirror.
//  - cov: XCD-grouped K-chunk swizzle (per-XCD L2 working set 3.1MB).
//  - S0: m-group swizzle (A-panel L2-resident, B streamed per group).
// ---------------------------------------------------------------------------

#define CH    512
#define NPIX  4096      // 64*64
#define HPAD  66
#define PPAD  4356      // 66*66
#define MROWS 4480      // padded row count for whitened-feature matrices
#define BANDW 2304      // S0T column band width (two bands cover 4416 cols)
#define BANDOFF 2112    // second band column offset
#define NS_ITERS 8

typedef unsigned short u16;
typedef __attribute__((ext_vector_type(8))) short short8;   // 8 bf16 (4 VGPRs)
typedef __attribute__((ext_vector_type(4))) float f32x4;    // MFMA C/D

__device__ __forceinline__ u16 bf16_rn(float x){
  union { float f; unsigned u; } v; v.f = x;
  unsigned u = v.u;
  return (u16)((u + 0x7FFFu + ((u >> 16) & 1u)) >> 16);
}
__device__ __forceinline__ float bf2f(u16 h){
  union { unsigned u; float f; } v; v.u = ((unsigned)h) << 16;
  return v.f;
}
__device__ __forceinline__ void split3(float x, u16& h, u16& m, u16& l){
  h = bf16_rn(x);
  float r1 = x - bf2f(h);
  m = bf16_rn(r1);
  l = bf16_rn(r1 - bf2f(m));
}
__device__ __forceinline__ void gll16(const void* g, void* l){
  __builtin_amdgcn_global_load_lds((const __attribute__((address_space(1))) unsigned*)g,
                                   (__attribute__((address_space(3))) unsigned*)l,
                                   16, 0, 0);
}
__device__ __forceinline__ f32x4 mfma_bf16(short8 a, short8 b, f32x4 c){
  return __builtin_amdgcn_mfma_f32_16x16x32_bf16(a, b, c, 0, 0, 0);
}

// ---------------------------------------------------------------------------
enum { M_COVP = 0, M_NST = 1, M_X3 = 2, M_WHITEN = 3, M_S0 = 4, M_COLOR = 5 };

struct GP {
  const u16 *Ah, *Am, *Al, *Bh, *Bm, *Bl;
  const u16 *Eh, *Em, *El, *Fh, *Fm, *Fl;   // alt A/B for M_X3 z>=4
  size_t sAz, sBz;           // per-z strides (elements)
  float* Cf;
  u16 *Ch, *Cm, *Cl;
  u16 *Gh, *Gm, *Gl;         // alt C for M_X3 z>=4
  size_t sCz;
  const float* scales;
  const float* meanv;
  int K;                     // row stride (elements)
  int Kit;                   // K iteration length for this launch
};

// C[m][n] = sum_k A[m][k]*B[n][k] with A,B stored as [row][K] bf16x3.
// 256 threads = 4 waves; TILE in {64,128}; wave computes (TILE/2)^2.
template<int TILE, int MODE>
__global__ __launch_bounds__(256, 2)
void gemm_sp(GP p){
  constexpr int MF = TILE / 32;
  constexpr bool SYM = (MODE == M_NST) || (MODE == M_X3);
  const int z = blockIdx.z;
  int m0, n0, zout = z;
  int kbase = 0;
  bool mirror = false;
  if constexpr (MODE == M_COVP){
    // XCD-grouped K-chunk swizzle: each XCD owns 2 of 16 (matrix,chunk) pairs
    const int lin = z*64 + blockIdx.y*8 + blockIdx.x;
    const int xcd = lin & 7, rest = lin >> 3;
    const int zc = xcd*2 + (rest >> 6);
    const int tile = rest & 63;
    m0 = (tile >> 3)*64; n0 = (tile & 7)*64;
    zout = zc;
    kbase = (zc & 3) * p.Kit;
  } else if constexpr (SYM){
    // triangular 8x8 block decode (bx in [0,36))
    int bx = blockIdx.x;
    int ty = (int)((sqrtf(8.f*bx + 1.f) - 1.f)*0.5f);
    while((ty+1)*(ty+2)/2 <= bx) ++ty;
    while(ty*(ty+1)/2 > bx) --ty;
    int tx = bx - ty*(ty+1)/2;
    m0 = ty*64; n0 = tx*64; mirror = (tx != ty);
  } else if constexpr (MODE == M_S0){
    // m-group swizzle: 7 groups of 5 m-blocks; A-panel (2MB) L2-resident
    const int lin = blockIdx.y*18 + blockIdx.x;
    const int mg = lin/90, r = lin%90;
    m0 = (mg*5 + (r%5))*128; n0 = (r/5)*128;
  } else {
    m0 = blockIdx.y*TILE; n0 = blockIdx.x*TILE;
  }

  const u16 *Ah, *Am, *Al, *Bh, *Bm, *Bl;
  if constexpr (MODE == M_X3){
    const size_t zb = (size_t)(z & 3) * CH * CH;
    if(z < 4){ Ah=p.Ah+zb; Am=p.Am+zb; Al=p.Al+zb; Bh=p.Bh+zb; Bm=p.Bm+zb; Bl=p.Bl+zb; }
    else     { Ah=p.Eh+zb; Am=p.Em+zb; Al=p.El+zb; Bh=p.Fh+zb; Bm=p.Fm+zb; Bl=p.Fl+zb; }
  } else {
    const int za = (MODE == M_COVP) ? (zout >> 2) : z;
    Ah = p.Ah + (size_t)za * p.sAz;
    Am = p.Am + (size_t)za * p.sAz;
    Al = p.Al + (size_t)za * p.sAz;
    Bh = p.Bh + (size_t)za * p.sBz;
    Bm = p.Bm + (size_t)za * p.sBz;
    Bl = p.Bl + (size_t)za * p.sBz;
  }

  const int tid = threadIdx.x, ln = tid & 63, wv = tid >> 6;
  const int wm = (wv >> 1) * (TILE/2), wn = (wv & 1) * (TILE/2);
  __shared__ __align__(16) u16 sAh[TILE*32], sAm[TILE*32], sAl[TILE*32];
  __shared__ __align__(16) u16 sBh[TILE*32], sBm[TILE*32], sBl[TILE*32];
  f32x4 acc[MF][MF];
#pragma unroll
  for(int i=0;i<MF;++i)
#pragma unroll
    for(int j=0;j<MF;++j) acc[i][j] = (f32x4)0.0f;
  const int K = p.K;
  for(int kk = 0; kk < p.Kit; kk += 32){
    const int k0 = kbase + kk;
#pragma unroll
    for(int s = tid; s < TILE*4; s += 256){      // 16B slots, 4 per row
      const int row = s >> 2, pos = s & 3;
      const int kc = pos ^ ((row >> 2) & 3);     // XOR swizzle
      const size_t ga = (size_t)(m0 + row) * K + k0 + kc*8;
      const size_t gb = (size_t)(n0 + row) * K + k0 + kc*8;
      gll16(Ah + ga, sAh + s*8);
      gll16(Am + ga, sAm + s*8);
      gll16(Al + ga, sAl + s*8);
      gll16(Bh + gb, sBh + s*8);
      gll16(Bm + gb, sBm + s*8);
      gll16(Bl + gb, sBl + s*8);
    }
    __syncthreads();
    short8 ah[MF], am[MF], al[MF], bh[MF], bm[MF], bl[MF];
#pragma unroll
    for(int i=0;i<MF;++i){
      const int ra = wm + i*16 + (ln & 15);
      const int rb = wn + i*16 + (ln & 15);
      const int pa = (ln >> 4) ^ ((ra >> 2) & 3);
      const int pb = (ln >> 4) ^ ((rb >> 2) & 3);
      const int ofa = ra*32 + pa*8;
      const int ofb = rb*32 + pb*8;
      ah[i] = *(const short8*)(sAh + ofa);
      am[i] = *(const short8*)(sAm + ofa);
      al[i] = *(const short8*)(sAl + ofa);
      bh[i] = *(const short8*)(sBh + ofb);
      bm[i] = *(const short8*)(sBm + ofb);
      bl[i] = *(const short8*)(sBl + ofb);
    }
#pragma unroll
    for(int i=0;i<MF;++i)
#pragma unroll
      for(int j=0;j<MF;++j){
        acc[i][j] = mfma_bf16(ah[i], bh[j], acc[i][j]);
        acc[i][j] = mfma_bf16(ah[i], bm[j], acc[i][j]);
        acc[i][j] = mfma_bf16(am[i], bh[j], acc[i][j]);
        acc[i][j] = mfma_bf16(am[i], bm[j], acc[i][j]);
        acc[i][j] = mfma_bf16(ah[i], bl[j], acc[i][j]);
        acc[i][j] = mfma_bf16(al[i], bh[j], acc[i][j]);
      }
    __syncthreads();
  }
  // epilogue: C/D layout col=lane&15, row=(lane>>4)*4+reg
  u16 *C0 = nullptr, *C1 = nullptr, *C2 = nullptr;
  if constexpr (MODE == M_NST){
    const size_t zb = (size_t)z * p.sCz;
    C0 = p.Ch + zb; C1 = p.Cm + zb; C2 = p.Cl + zb;
  } else if constexpr (MODE == M_X3){
    const size_t zb = (size_t)(z & 3) * p.sCz;
    if(z < 4){ C0 = p.Ch + zb; C1 = p.Cm + zb; C2 = p.Cl + zb; }
    else     { C0 = p.Gh + zb; C1 = p.Gm + zb; C2 = p.Gl + zb; }
  }
#pragma unroll
  for(int i=0;i<MF;++i)
#pragma unroll
    for(int j=0;j<MF;++j)
#pragma unroll
      for(int r=0;r<4;++r){
        const int m = m0 + wm + i*16 + (ln >> 4)*4 + r;
        const int n = n0 + wn + j*16 + (ln & 15);
        float v = acc[i][j][r];
        if constexpr (MODE == M_COVP){
          p.Cf[(size_t)zout * p.sCz + (size_t)m * CH + n] = v;   // raw partial
        } else if constexpr (MODE == M_NST || MODE == M_X3){
          if constexpr (MODE == M_NST) v = -0.5f*v + ((m == n) ? 1.5f : 0.0f);
          u16 h, mm2, l; split3(v, h, mm2, l);
          C0[(size_t)m*CH + n] = h; C1[(size_t)m*CH + n] = mm2; C2[(size_t)m*CH + n] = l;
          if(mirror){
            C0[(size_t)n*CH + m] = h; C1[(size_t)n*CH + m] = mm2; C2[(size_t)n*CH + m] = l;
          }
        } else if constexpr (MODE == M_WHITEN){
          v *= p.scales[z*4 + 3];                 // rsqrt(c)
          const int prow = ((m >> 6) + 1)*HPAD + (m & 63) + 1;
          u16 h, mm2, l; split3(v, h, mm2, l);
          const size_t o = (size_t)z*p.sCz + (size_t)prow*CH + n;
          p.Ch[o] = h; p.Cm[o] = mm2; p.Cl[o] = l;
        } else if constexpr (MODE == M_S0){
          p.Cf[(size_t)m * BANDW + n] = v;
        } else {                                  // M_COLOR
          const float sc = p.scales[(2+z)*4 + 2]; // sqrt(c)
          const float mu = p.meanv[(2+z)*CH + m];
          p.Cf[(size_t)z*p.sCz + (size_t)m*NPIX + n] = v*sc + mu;
        }
      }
}

// ---------------- cov reduce: sum 4 K-chunks, scale 1/4095 ------------------
__global__ __launch_bounds__(256)
void cov_reduce_kernel(const float* __restrict__ covp, float* __restrict__ cov){
  size_t t = (size_t)blockIdx.x * 256 + threadIdx.x;   // 4*512*512
  int z = (int)(t >> 18);
  size_t e = t & 262143;
  float s = 0.f;
#pragma unroll
  for(int c = 0; c < 4; ++c) s += covp[((size_t)(z*4 + c) << 18) + e];
  cov[t] = s * (1.0f / 4095.0f);
}

// ---------------- power iteration -> lambda_max -> NS scaling ---------------
// Rayleigh quotient <= lambda_max always; x1.2 margin. NS converges for
// spectrum in (0,3), so under-converged estimates are safe.
__global__ __launch_bounds__(256)
void pow_scale_kernel(const float* __restrict__ cov, float* __restrict__ scales){
  const int z = blockIdx.x;
  const float* A = cov + (size_t)z * CH * CH;
  __shared__ float v[CH], w[CH], red[256];
  const int t = threadIdx.x;
  v[t] = 1.0f; v[t + 256] = 1.0f;
  __syncthreads();
  for(int it = 0; it < 14; ++it){
#pragma unroll
    for(int rr = 0; rr < 2; ++rr){
      const int r = t + rr*256;
      float s = 0.f;
      for(int c = 0; c < CH; ++c) s = fmaf(A[(size_t)r*CH + c], v[c], s);
      w[r] = s;
    }
    __syncthreads();
    float mx = fmaxf(fabsf(w[t]), fabsf(w[t + 256]));
    red[t] = mx; __syncthreads();
    for(int o = 128; o; o >>= 1){
      if(t < o) red[t] = fmaxf(red[t], red[t + o]);
      __syncthreads();
    }
    const float inv = 1.0f / red[0];
    __syncthreads();
    v[t] = w[t] * inv; v[t + 256] = w[t + 256] * inv;
    __syncthreads();
  }
#pragma unroll
  for(int rr = 0; rr < 2; ++rr){
    const int r = t + rr*256;
    float s = 0.f;
    for(int c = 0; c < CH; ++c) s = fmaf(A[(size_t)r*CH + c], v[c], s);
    w[r] = s;
  }
  __syncthreads();
  red[t] = v[t]*w[t] + v[t+256]*w[t+256]; __syncthreads();
  for(int o = 128; o; o >>= 1){ if(t < o) red[t] += red[t + o]; __syncthreads(); }
  const float num = red[0]; __syncthreads();
  red[t] = v[t]*v[t] + v[t+256]*v[t+256]; __syncthreads();
  for(int o = 128; o; o >>= 1){ if(t < o) red[t] += red[t + o]; __syncthreads(); }
  const float den = red[0];
  if(t == 0){
    const float c = 1.2f * (num / den);
    scales[z*4+0] = c;
    scales[z*4+1] = 1.0f / c;
    scales[z*4+2] = sqrtf(c);
    scales[z*4+3] = rsqrtf(c);
  }
}

// ---------------- per-(matrix,channel) mean over 4096 pixels ----------------
__global__ __launch_bounds__(256)
void mean_kernel(const float* __restrict__ content, const float* __restrict__ style,
                 float* __restrict__ meanv){
  int mm = blockIdx.x;           // 0..2047
  int z = mm >> 9, c = mm & 511;
  const float* X = ((z < 2) ? content + (size_t)z * CH * NPIX
                            : style   + (size_t)(z - 2) * CH * NPIX) + (size_t)c * NPIX;
  float s = 0.f;
  for(int i = threadIdx.x; i < NPIX; i += 256) s += X[i];
  __shared__ float red[256];
  red[threadIdx.x] = s; __syncthreads();
  for(int w = 128; w > 0; w >>= 1){
    if(threadIdx.x < w) red[threadIdx.x] += red[threadIdx.x + w];
    __syncthreads();
  }
  if(threadIdx.x == 0) meanv[mm] = red[0] * (1.0f / NPIX);
}

// ------- center + bf16x3 split, emit both [c][pix] and [pix][c] layouts -----
__global__ __launch_bounds__(256)
void center_split_kernel(const float* __restrict__ content, const float* __restrict__ style,
                         const float* __restrict__ meanv,
                         u16* __restrict__ Xch, u16* __restrict__ Xcm, u16* __restrict__ Xcl,
                         u16* __restrict__ XcTh, u16* __restrict__ XcTm, u16* __restrict__ XcTl){
  int z = blockIdx.z;
  const float* X = (z < 2) ? content + (size_t)z * CH * NPIX
                           : style   + (size_t)(z - 2) * CH * NPIX;
  int p0 = blockIdx.x * 64, c0 = blockIdx.y * 64;
  __shared__ float T[64][65];
  int col = threadIdx.x & 63, rq = threadIdx.x >> 6;
#pragma unroll
  for(int i = 0; i < 16; ++i){
    int r = i*4 + rq;
    int c = c0 + r;
    float v = X[(size_t)c * NPIX + p0 + col] - meanv[z*CH + c];
    u16 h, m, l; split3(v, h, m, l);
    size_t o = (size_t)(z*CH + c) * NPIX + p0 + col;
    Xch[o] = h; Xcm[o] = m; Xcl[o] = l;
    T[col][r] = v;
  }
  __syncthreads();
#pragma unroll
  for(int i = 0; i < 16; ++i){
    int r = i*4 + rq;                 // pixel-in-tile
    float v = T[r][col];
    u16 h, m, l; split3(v, h, m, l);
    size_t o = (size_t)(z*NPIX + p0 + r) * CH + c0 + col;
    XcTh[o] = h; XcTm[o] = m; XcTl[o] = l;
  }
}

// ---------------- Y0 = cov/c (x3), Z0 = I (x3) ------------------------------
__global__ __launch_bounds__(256)
void ns_init_kernel(const float* __restrict__ cov, const float* __restrict__ scales,
                    u16* Yh, u16* Ym, u16* Yl, u16* Zh, u16* Zm, u16* Zl){
  size_t t = (size_t)blockIdx.x * 256 + threadIdx.x;   // 4*512*512
  int z = (int)(t >> 18);
  size_t e = t & 262143;
  int row = (int)(e >> 9), col = (int)(e & 511);
  float v = cov[t] * scales[z*4+1];
  u16 h, m, l; split3(v, h, m, l);
  Yh[t] = h; Ym[t] = m; Yl[t] = l;
  Zh[t] = (row == col) ? (u16)0x3F80 : (u16)0;
  Zm[t] = 0; Zl[t] = 0;
}

// ---------------- cn2[p'] = ||whitened style column||^2 ---------------------
__global__ __launch_bounds__(256)
void cn2_kernel(const u16* __restrict__ Wh, const u16* __restrict__ Wm,
                const u16* __restrict__ Wl, float* __restrict__ cn2){
  int b = blockIdx.y;
  int row = blockIdx.x * 16 + (threadIdx.x >> 4);
  int t = threadIdx.x & 15;
  float s = 0.f;
  if(row < PPAD){
    size_t base = ((size_t)(2 + b) * MROWS + row) * CH;
    for(int ch = t; ch < 64; ch += 16){
      uint4 hv = *(const uint4*)(Wh + base + ch*8);
      uint4 mv = *(const uint4*)(Wm + base + ch*8);
      uint4 lv = *(const uint4*)(Wl + base + ch*8);
      const unsigned* hw = (const unsigned*)&hv;
      const unsigned* mw = (const unsigned*)&mv;
      const unsigned* lw = (const unsigned*)&lv;
#pragma unroll
      for(int w = 0; w < 4; ++w){
        float v0 = bf2f((u16)(hw[w] & 0xFFFF)) + bf2f((u16)(mw[w] & 0xFFFF)) + bf2f((u16)(lw[w] & 0xFFFF));
        float v1 = bf2f((u16)(hw[w] >> 16))    + bf2f((u16)(mw[w] >> 16))    + bf2f((u16)(lw[w] >> 16));
        s = fmaf(v0, v0, s); s = fmaf(v1, v1, s);
      }
    }
  }
  for(int off = 8; off; off >>= 1) s += __shfl_down(s, off, 16);
  if(t == 0 && row < PPAD) cn2[b*PPAD + row] = s;
}

// ---------------- rnorm[p] = 1/(sqrt(sum of 9 taps)+1e-5) -------------------
__global__ __launch_bounds__(256)
void rnorm_kernel(const float* __restrict__ cn2, float* __restrict__ rnorm){
  int b = blockIdx.y;
  int p = blockIdx.x * 256 + threadIdx.x;   // 0..4095
  int py = p >> 6, px = p & 63;
  const float* c2 = cn2 + (size_t)b * PPAD + (size_t)py * HPAD + px;
  float s = 0.f;
#pragma unroll
  for(int i = 0; i < 3; ++i)
#pragma unroll
    for(int j = 0; j < 3; ++j) s += c2[i * HPAD + j];
  rnorm[b * 4096 + p] = 1.0f / (sqrtf(s) + 1e-5f);
}

// ---------------- per-p-chunk argmax of 9-tap stencil score (banded) --------
__global__ __launch_bounds__(256)
void score_partial_kernel(const float* __restrict__ S0T, const float* __restrict__ rnorm,
                          float* __restrict__ pmax, int* __restrict__ pidx,
                          int b, int qy0, int colbase){
  int q = qy0*64 + blockIdx.y * 256 + threadIdx.x;
  int chunk = blockIdx.x;
  int qy = q >> 6, qx = q & 63;
  int qcol = qy * HPAD + qx - colbase;
  const float* rn = rnorm + b * 4096;
  float best = -1e30f; int bestp = 0;
  for(int p = chunk * 64; p < chunk * 64 + 64; ++p){
    int py = p >> 6, px = p & 63;
    const float* base = S0T + (size_t)(py * HPAD + px) * BANDW + qcol;
    float s = 0.f;
#pragma unroll
    for(int i = 0; i < 3; ++i)
#pragma unroll
      for(int j = 0; j < 3; ++j)
        s += base[(size_t)(i * HPAD + j) * (BANDW + 1)];
    s *= rn[p];
    if(s > best){ best = s; bestp = p; }
  }
  pmax[(size_t)chunk * 4096 + q] = best;
  pidx[(size_t)chunk * 4096 + q] = bestp;
}

__global__ __launch_bounds__(256)
void argmax_merge_kernel(const float* __restrict__ pmax, const int* __restrict__ pidx,
                         int* __restrict__ idx, int b){
  int q = blockIdx.x * 256 + threadIdx.x;
  float best = -1e30f; int bp = 0;
  for(int ch = 0; ch < 64; ++ch){
    float v = pmax[(size_t)ch * 4096 + q];
    if(v > best){ best = v; bp = pidx[(size_t)ch * 4096 + q]; }
  }
  idx[b * 4096 + q] = bp;
}

// ---------------- gather matched patches, overlap-add, write RT x3 ----------
__global__ __launch_bounds__(256)
void gather_kernel(const u16* __restrict__ Wh, const u16* __restrict__ Wm,
                   const u16* __restrict__ Wl, const int* __restrict__ idx,
                   u16* __restrict__ RTh, u16* __restrict__ RTm, u16* __restrict__ RTl){
  int g = blockIdx.x * 256 + threadIdx.x;   // 2*4096*64
  int cg = g & 63;
  int pix = (g >> 6) & 4095;
  int b = g >> 18;
  int y = pix >> 6, x = pix & 63;
  const int* idxb = idx + b * 4096;
  size_t matbase = (size_t)(2 + b) * MROWS * CH;
  float a8[8] = {0,0,0,0,0,0,0,0};
  int cnt = 0;
#pragma unroll
  for(int i = 0; i < 3; ++i){
    int qy = y + 1 - i;
    if((unsigned)qy >= 64u) continue;
#pragma unroll
    for(int j = 0; j < 3; ++j){
      int qx = x + 1 - j;
      if((unsigned)qx >= 64u) continue;
      int p = idxb[qy * 64 + qx];
      int row = ((p >> 6) + i) * HPAD + (p & 63) + j;
      size_t off = matbase + (size_t)row * CH + cg * 8;
      uint4 hv = *(const uint4*)(Wh + off);
      uint4 mv = *(const uint4*)(Wm + off);
      uint4 lv = *(const uint4*)(Wl + off);
      const unsigned* hw = (const unsigned*)&hv;
      const unsigned* mw = (const unsigned*)&mv;
      const unsigned* lw = (const unsigned*)&lv;
#pragma unroll
      for(int w = 0; w < 4; ++w){
        a8[2*w]   += bf2f((u16)(hw[w] & 0xFFFF)) + bf2f((u16)(mw[w] & 0xFFFF)) + bf2f((u16)(lw[w] & 0xFFFF));
        a8[2*w+1] += bf2f((u16)(hw[w] >> 16))    + bf2f((u16)(mw[w] >> 16))    + bf2f((u16)(lw[w] >> 16));
      }
      ++cnt;
    }
  }
  float inv = 1.0f / (float)cnt;
  u16 oh[8], om[8], ol[8];
#pragma unroll
  for(int k = 0; k < 8; ++k){
    float v = a8[k] * inv;
    split3(v, oh[k], om[k], ol[k]);
  }
  size_t ro = ((size_t)(b * 4096 + pix)) * CH + cg * 8;
  *(uint4*)(RTh + ro) = *(const uint4*)oh;
  *(uint4*)(RTm + ro) = *(const uint4*)om;
  *(uint4*)(RTl + ro) = *(const uint4*)ol;
}

// ---------------------------------------------------------------------------
extern "C" void kernel_launch(void* const* d_in, const int* in_sizes, int n_in,
                              void* d_out, int out_size, void* d_ws, size_t ws_size,
                              hipStream_t stream){
  (void)in_sizes; (void)n_in; (void)out_size; (void)ws_size;
  const float* content = (const float*)d_in[0];
  const float* style   = (const float*)d_in[1];
  float* out = (float*)d_out;

  char* base = (char*)d_ws;
  size_t off = 0;
  auto take = [&](size_t nbytes) -> char* {
    char* p = base + off;
    off = (off + nbytes + 255) & ~(size_t)255;
    return p;
  };
  const size_t MAT = (size_t)CH*CH*2;            // 512x512 bf16 bytes
  const size_t FEAT = (size_t)CH*NPIX*2;         // 512x4096 bf16 bytes
  const size_t WMAT = (size_t)MROWS*CH*2;        // 4480x512 bf16 bytes

  float* meanv  = (float*)take((size_t)4*CH*sizeof(float));
  float* scales = (float*)take(256);
  float* cov    = (float*)take((size_t)4*CH*CH*sizeof(float));
  u16 *Yh=(u16*)take(4*MAT), *Ym=(u16*)take(4*MAT), *Yl=(u16*)take(4*MAT);
  u16 *Zh=(u16*)take(4*MAT), *Zm=(u16*)take(4*MAT), *Zl=(u16*)take(4*MAT);
  u16 *Th=(u16*)take(4*MAT), *Tm=(u16*)take(4*MAT), *Tl=(u16*)take(4*MAT);
  u16 *Ynh=(u16*)take(4*MAT), *Ynm=(u16*)take(4*MAT), *Ynl=(u16*)take(4*MAT);
  u16 *Znh=(u16*)take(4*MAT), *Znm=(u16*)take(4*MAT), *Znl=(u16*)take(4*MAT);
  // cov K-split partials (16 MB) alias the NS temp region (dead at cov time)
  float* covp = (float*)Th;
  // P1: Xc x3 (center->cov)  then  W x3 (post-NS -> end)
  char* P1 = take(3*(size_t)4*WMAT);
  u16 *Xch=(u16*)P1, *Xcm=(u16*)(P1+4*FEAT), *Xcl=(u16*)(P1+8*FEAT);
  u16 *Wh=(u16*)P1, *Wm=(u16*)(P1+4*WMAT), *Wl=(u16*)(P1+8*WMAT);
  // P0: XcT x3 (center->whiten), then S0T band, then RT x3
  char* P0 = take(3*(size_t)4*FEAT);
  u16 *XcTh=(u16*)P0, *XcTm=(u16*)(P0+4*FEAT), *XcTl=(u16*)(P0+8*FEAT);
  float* S0T = (float*)P0;
  u16 *RTh=(u16*)P0, *RTm=(u16*)(P0+2*FEAT), *RTl=(u16*)(P0+4*FEAT);
  float* cn2    = (float*)take((size_t)2*PPAD*sizeof(float));
  float* rnormb = (float*)take((size_t)2*4096*sizeof(float));
  float* pmax   = (float*)take((size_t)64*4096*sizeof(float));
  int*   pidx   = (int*)  take((size_t)64*4096*sizeof(int));
  int*   idxb   = (int*)  take((size_t)2*4096*sizeof(int));

  mean_kernel<<<2048, 256, 0, stream>>>(content, style, meanv);
  center_split_kernel<<<dim3(64, 8, 4), 256, 0, stream>>>(content, style, meanv,
                                                          Xch, Xcm, Xcl, XcTh, XcTm, XcTl);
  // cov partials: XCD-grouped swizzle, 1024 blocks
  {
    GP g{}; g.Ah=Xch; g.Am=Xcm; g.Al=Xcl; g.Bh=Xch; g.Bm=Xcm; g.Bl=Xcl;
    g.sAz = g.sBz = (size_t)CH*NPIX; g.Cf = covp; g.sCz = (size_t)CH*CH;
    g.K = NPIX; g.Kit = 1024;
    gemm_sp<64, M_COVP><<<dim3(8, 8, 16), 256, 0, stream>>>(g);
  }
  cov_reduce_kernel<<<4096, 256, 0, stream>>>(covp, cov);
  pow_scale_kernel<<<4, 256, 0, stream>>>(cov, scales);
  ns_init_kernel<<<4096, 256, 0, stream>>>(cov, scales, Yh, Ym, Yl, Zh, Zm, Zl);

  u16 *Ach[3]={Yh,Ym,Yl}, *Bch[3]={Zh,Zm,Zl}, *An[3]={Ynh,Ynm,Ynl}, *Bn[3]={Znh,Znm,Znl};
  for(int it = 0; it < NS_ITERS; ++it){
    // T = 1.5I - 0.5 Z*Y  (symmetric: 36 triangle blocks, mirrored)
    GP t{}; t.Ah=Bch[0]; t.Am=Bch[1]; t.Al=Bch[2];            // Z
    t.Bh=Ach[0]; t.Bm=Ach[1]; t.Bl=Ach[2];                    // Y (symmetric)
    t.sAz = t.sBz = (size_t)CH*CH; t.Ch=Th; t.Cm=Tm; t.Cl=Tl; t.sCz=(size_t)CH*CH;
    t.K = CH; t.Kit = CH;
    gemm_sp<64, M_NST><<<dim3(36, 1, 4), 256, 0, stream>>>(t);
    // z<4: Yn = Y*T ; z>=4: Zn = T*Z  (both symmetric, mirrored)
    GP u{}; u.Ah=Ach[0]; u.Am=Ach[1]; u.Al=Ach[2];            // Y
    u.Bh=Th; u.Bm=Tm; u.Bl=Tl;                                // T
    u.Eh=Th; u.Em=Tm; u.El=Tl;                                // T
    u.Fh=Bch[0]; u.Fm=Bch[1]; u.Fl=Bch[2];                    // Z
    u.Ch=An[0]; u.Cm=An[1]; u.Cl=An[2];
    u.Gh=Bn[0]; u.Gm=Bn[1]; u.Gl=Bn[2];
    u.sCz=(size_t)CH*CH; u.K = CH; u.Kit = CH;
    gemm_sp<64, M_X3><<<dim3(36, 1, 8), 256, 0, stream>>>(u);
    for(int c = 0; c < 3; ++c){ u16* tmp=Ach[c]; Ach[c]=An[c]; An[c]=tmp;
                                tmp=Bch[c]; Bch[c]=Bn[c]; Bn[c]=tmp; }
  }

  // W (padded, zero borders) -- Xc region is dead now; Wh/Wm/Wl alias it
  hipMemsetAsync(Wh, 0, 4*WMAT, stream);
  hipMemsetAsync(Wm, 0, 4*WMAT, stream);
  hipMemsetAsync(Wl, 0, 4*WMAT, stream);
  // W[pix][c] = XcT * Z  (Z symmetric), scaled by rsqrt(c)
  {
    GP w{}; w.Ah=XcTh; w.Am=XcTm; w.Al=XcTl; w.sAz=(size_t)NPIX*CH;
    w.Bh=Bch[0]; w.Bm=Bch[1]; w.Bl=Bch[2]; w.sBz=(size_t)CH*CH;
    w.Ch=Wh; w.Cm=Wm; w.Cl=Wl; w.sCz=(size_t)MROWS*CH; w.scales=scales;
    w.K = CH; w.Kit = CH;
    gemm_sp<128, M_WHITEN><<<dim3(4, 32, 4), 256, 0, stream>>>(w);
  }
  cn2_kernel<<<dim3(273, 2), 256, 0, stream>>>(Wh, Wm, Wl, cn2);
  rnorm_kernel<<<dim3(16, 2), 256, 0, stream>>>(cn2, rnormb);

  for(int b = 0; b < 2; ++b){
    for(int band = 0; band < 2; ++band){
      GP s{};
      s.Ah = Wh + (size_t)(2+b)*MROWS*CH; s.Am = Wm + (size_t)(2+b)*MROWS*CH; s.Al = Wl + (size_t)(2+b)*MROWS*CH;
      size_t bo = (size_t)b*MROWS*CH + (size_t)(band ? BANDOFF : 0)*CH;
      s.Bh = Wh + bo; s.Bm = Wm + bo; s.Bl = Wl + bo;
      s.sAz = s.sBz = 0; s.Cf = S0T; s.sCz = 0; s.K = CH; s.Kit = CH;
      gemm_sp<128, M_S0><<<dim3(BANDW/128, MROWS/128, 1), 256, 0, stream>>>(s);
      score_partial_kernel<<<dim3(64, 8), 256, 0, stream>>>(S0T, rnormb, pmax, pidx,
                                                            b, band ? 32 : 0,
                                                            band ? BANDOFF : 0);
    }
    argmax_merge_kernel<<<16, 256, 0, stream>>>(pmax, pidx, idxb, b);
  }

  gather_kernel<<<2048, 256, 0, stream>>>(Wh, Wm, Wl, idxb, RTh, RTm, RTl);
  // out = Ys * R * sqrt(c) + mu   (Ys symmetric)
  {
    GP c{}; c.Ah = Ach[0] + 2*(size_t)CH*CH; c.Am = Ach[1] + 2*(size_t)CH*CH; c.Al = Ach[2] + 2*(size_t)CH*CH;
    c.sAz = (size_t)CH*CH;
    c.Bh = RTh; c.Bm = RTm; c.Bl = RTl; c.sBz = (size_t)NPIX*CH;
    c.Cf = out; c.sCz = (size_t)CH*NPIX; c.scales = scales; c.meanv = meanv;
    c.K = CH; c.Kit = CH;
    gemm_sp<128, M_COLOR><<<dim3(32, 4, 2), 256, 0, stream>>>(c);
  }
}

// Round 5
// 1375.219 us; speedup vs baseline: 1.1898x; 1.1898x over previous
//
#include <hip/hip_runtime.h>

// ---------------------------------------------------------------------------
// StyleDecorator, round 5: bf16x3 (6-term) MFMA everywhere.
//  - inf-norm scale (fast, round-2 proven) + 10 NS iters. pow_scale (429us
//    serial, round-4 regression) removed.
//  - NS symmetric triangle (36 blocks) + mirror write (round-4, validated).
//  - cov: plain K-split x4 (round-3 measured 86us; XCD swizzle reverted).
//  - S0: m-group swizzle (A-panel L2-resident).
// ---------------------------------------------------------------------------

#define CH    512
#define NPIX  4096      // 64*64
#define HPAD  66
#define PPAD  4356      // 66*66
#define MROWS 4480      // padded row count for whitened-feature matrices
#define BANDW 2304      // S0T column band width (two bands cover 4416 cols)
#define BANDOFF 2112    // second band column offset
#define NS_ITERS 10

typedef unsigned short u16;
typedef __attribute__((ext_vector_type(8))) short short8;   // 8 bf16 (4 VGPRs)
typedef __attribute__((ext_vector_type(4))) float f32x4;    // MFMA C/D

__device__ __forceinline__ u16 bf16_rn(float x){
  union { float f; unsigned u; } v; v.f = x;
  unsigned u = v.u;
  return (u16)((u + 0x7FFFu + ((u >> 16) & 1u)) >> 16);
}
__device__ __forceinline__ float bf2f(u16 h){
  union { unsigned u; float f; } v; v.u = ((unsigned)h) << 16;
  return v.f;
}
__device__ __forceinline__ void split3(float x, u16& h, u16& m, u16& l){
  h = bf16_rn(x);
  float r1 = x - bf2f(h);
  m = bf16_rn(r1);
  l = bf16_rn(r1 - bf2f(m));
}
__device__ __forceinline__ void gll16(const void* g, void* l){
  __builtin_amdgcn_global_load_lds((const __attribute__((address_space(1))) unsigned*)g,
                                   (__attribute__((address_space(3))) unsigned*)l,
                                   16, 0, 0);
}
__device__ __forceinline__ f32x4 mfma_bf16(short8 a, short8 b, f32x4 c){
  return __builtin_amdgcn_mfma_f32_16x16x32_bf16(a, b, c, 0, 0, 0);
}

// ---------------------------------------------------------------------------
enum { M_COVP = 0, M_NST = 1, M_X3 = 2, M_WHITEN = 3, M_S0 = 4, M_COLOR = 5 };

struct GP {
  const u16 *Ah, *Am, *Al, *Bh, *Bm, *Bl;
  const u16 *Eh, *Em, *El, *Fh, *Fm, *Fl;   // alt A/B for M_X3 z>=4
  size_t sAz, sBz;           // per-z strides (elements)
  float* Cf;
  u16 *Ch, *Cm, *Cl;
  u16 *Gh, *Gm, *Gl;         // alt C for M_X3 z>=4
  size_t sCz;
  const float* scales;
  const float* meanv;
  int K;                     // row stride (elements)
  int Kit;                   // K iteration length for this launch
};

// C[m][n] = sum_k A[m][k]*B[n][k] with A,B stored as [row][K] bf16x3.
// 256 threads = 4 waves; TILE in {64,128}; wave computes (TILE/2)^2.
template<int TILE, int MODE>
__global__ __launch_bounds__(256, 2)
void gemm_sp(GP p){
  constexpr int MF = TILE / 32;
  constexpr bool SYM = (MODE == M_NST) || (MODE == M_X3);
  const int z = blockIdx.z;
  int m0, n0;
  int kbase = 0;
  bool mirror = false;
  if constexpr (MODE == M_COVP){
    m0 = blockIdx.y*64; n0 = blockIdx.x*64;
    kbase = (z & 3) * p.Kit;
  } else if constexpr (SYM){
    // triangular 8x8 block decode (bx in [0,36))
    int bx = blockIdx.x;
    int ty = (int)((sqrtf(8.f*bx + 1.f) - 1.f)*0.5f);
    while((ty+1)*(ty+2)/2 <= bx) ++ty;
    while(ty*(ty+1)/2 > bx) --ty;
    int tx = bx - ty*(ty+1)/2;
    m0 = ty*64; n0 = tx*64; mirror = (tx != ty);
  } else if constexpr (MODE == M_S0){
    // m-group swizzle: 7 groups of 5 m-blocks; A-panel (2MB) L2-resident
    const int lin = blockIdx.y*18 + blockIdx.x;
    const int mg = lin/90, r = lin%90;
    m0 = (mg*5 + (r%5))*128; n0 = (r/5)*128;
  } else {
    m0 = blockIdx.y*TILE; n0 = blockIdx.x*TILE;
  }

  const u16 *Ah, *Am, *Al, *Bh, *Bm, *Bl;
  if constexpr (MODE == M_X3){
    const size_t zb = (size_t)(z & 3) * CH * CH;
    if(z < 4){ Ah=p.Ah+zb; Am=p.Am+zb; Al=p.Al+zb; Bh=p.Bh+zb; Bm=p.Bm+zb; Bl=p.Bl+zb; }
    else     { Ah=p.Eh+zb; Am=p.Em+zb; Al=p.El+zb; Bh=p.Fh+zb; Bm=p.Fm+zb; Bl=p.Fl+zb; }
  } else {
    const int za = (MODE == M_COVP) ? (z >> 2) : z;
    Ah = p.Ah + (size_t)za * p.sAz;
    Am = p.Am + (size_t)za * p.sAz;
    Al = p.Al + (size_t)za * p.sAz;
    Bh = p.Bh + (size_t)za * p.sBz;
    Bm = p.Bm + (size_t)za * p.sBz;
    Bl = p.Bl + (size_t)za * p.sBz;
  }

  const int tid = threadIdx.x, ln = tid & 63, wv = tid >> 6;
  const int wm = (wv >> 1) * (TILE/2), wn = (wv & 1) * (TILE/2);
  __shared__ __align__(16) u16 sAh[TILE*32], sAm[TILE*32], sAl[TILE*32];
  __shared__ __align__(16) u16 sBh[TILE*32], sBm[TILE*32], sBl[TILE*32];
  f32x4 acc[MF][MF];
#pragma unroll
  for(int i=0;i<MF;++i)
#pragma unroll
    for(int j=0;j<MF;++j) acc[i][j] = (f32x4)0.0f;
  const int K = p.K;
  for(int kk = 0; kk < p.Kit; kk += 32){
    const int k0 = kbase + kk;
#pragma unroll
    for(int s = tid; s < TILE*4; s += 256){      // 16B slots, 4 per row
      const int row = s >> 2, pos = s & 3;
      const int kc = pos ^ ((row >> 2) & 3);     // XOR swizzle
      const size_t ga = (size_t)(m0 + row) * K + k0 + kc*8;
      const size_t gb = (size_t)(n0 + row) * K + k0 + kc*8;
      gll16(Ah + ga, sAh + s*8);
      gll16(Am + ga, sAm + s*8);
      gll16(Al + ga, sAl + s*8);
      gll16(Bh + gb, sBh + s*8);
      gll16(Bm + gb, sBm + s*8);
      gll16(Bl + gb, sBl + s*8);
    }
    __syncthreads();
    short8 ah[MF], am[MF], al[MF], bh[MF], bm[MF], bl[MF];
#pragma unroll
    for(int i=0;i<MF;++i){
      const int ra = wm + i*16 + (ln & 15);
      const int rb = wn + i*16 + (ln & 15);
      const int pa = (ln >> 4) ^ ((ra >> 2) & 3);
      const int pb = (ln >> 4) ^ ((rb >> 2) & 3);
      const int ofa = ra*32 + pa*8;
      const int ofb = rb*32 + pb*8;
      ah[i] = *(const short8*)(sAh + ofa);
      am[i] = *(const short8*)(sAm + ofa);
      al[i] = *(const short8*)(sAl + ofa);
      bh[i] = *(const short8*)(sBh + ofb);
      bm[i] = *(const short8*)(sBm + ofb);
      bl[i] = *(const short8*)(sBl + ofb);
    }
#pragma unroll
    for(int i=0;i<MF;++i)
#pragma unroll
      for(int j=0;j<MF;++j){
        acc[i][j] = mfma_bf16(ah[i], bh[j], acc[i][j]);
        acc[i][j] = mfma_bf16(ah[i], bm[j], acc[i][j]);
        acc[i][j] = mfma_bf16(am[i], bh[j], acc[i][j]);
        acc[i][j] = mfma_bf16(am[i], bm[j], acc[i][j]);
        acc[i][j] = mfma_bf16(ah[i], bl[j], acc[i][j]);
        acc[i][j] = mfma_bf16(al[i], bh[j], acc[i][j]);
      }
    __syncthreads();
  }
  // epilogue: C/D layout col=lane&15, row=(lane>>4)*4+reg
  u16 *C0 = nullptr, *C1 = nullptr, *C2 = nullptr;
  if constexpr (MODE == M_NST){
    const size_t zb = (size_t)z * p.sCz;
    C0 = p.Ch + zb; C1 = p.Cm + zb; C2 = p.Cl + zb;
  } else if constexpr (MODE == M_X3){
    const size_t zb = (size_t)(z & 3) * p.sCz;
    if(z < 4){ C0 = p.Ch + zb; C1 = p.Cm + zb; C2 = p.Cl + zb; }
    else     { C0 = p.Gh + zb; C1 = p.Gm + zb; C2 = p.Gl + zb; }
  }
#pragma unroll
  for(int i=0;i<MF;++i)
#pragma unroll
    for(int j=0;j<MF;++j)
#pragma unroll
      for(int r=0;r<4;++r){
        const int m = m0 + wm + i*16 + (ln >> 4)*4 + r;
        const int n = n0 + wn + j*16 + (ln & 15);
        float v = acc[i][j][r];
        if constexpr (MODE == M_COVP){
          p.Cf[(size_t)z * p.sCz + (size_t)m * CH + n] = v;   // raw partial
        } else if constexpr (MODE == M_NST || MODE == M_X3){
          if constexpr (MODE == M_NST) v = -0.5f*v + ((m == n) ? 1.5f : 0.0f);
          u16 h, mm2, l; split3(v, h, mm2, l);
          C0[(size_t)m*CH + n] = h; C1[(size_t)m*CH + n] = mm2; C2[(size_t)m*CH + n] = l;
          if(mirror){
            C0[(size_t)n*CH + m] = h; C1[(size_t)n*CH + m] = mm2; C2[(size_t)n*CH + m] = l;
          }
        } else if constexpr (MODE == M_WHITEN){
          v *= p.scales[z*4 + 3];                 // rsqrt(c)
          const int prow = ((m >> 6) + 1)*HPAD + (m & 63) + 1;
          u16 h, mm2, l; split3(v, h, mm2, l);
          const size_t o = (size_t)z*p.sCz + (size_t)prow*CH + n;
          p.Ch[o] = h; p.Cm[o] = mm2; p.Cl[o] = l;
        } else if constexpr (MODE == M_S0){
          p.Cf[(size_t)m * BANDW + n] = v;
        } else {                                  // M_COLOR
          const float sc = p.scales[(2+z)*4 + 2]; // sqrt(c)
          const float mu = p.meanv[(2+z)*CH + m];
          p.Cf[(size_t)z*p.sCz + (size_t)m*NPIX + n] = v*sc + mu;
        }
      }
}

// ---------------- cov reduce: sum 4 K-chunks, scale 1/4095 ------------------
__global__ __launch_bounds__(256)
void cov_reduce_kernel(const float* __restrict__ covp, float* __restrict__ cov){
  size_t t = (size_t)blockIdx.x * 256 + threadIdx.x;   // 4*512*512
  int z = (int)(t >> 18);
  size_t e = t & 262143;
  float s = 0.f;
#pragma unroll
  for(int c = 0; c < 4; ++c) s += covp[((size_t)(z*4 + c) << 18) + e];
  cov[t] = s * (1.0f / 4095.0f);
}

// ---------------- scale[z] = {c, 1/c, sqrt(c), rsqrt(c)}, c = ||A||_inf -----
__global__ __launch_bounds__(256)
void scale_kernel(const float* __restrict__ cov, float* __restrict__ scales){
  int z = blockIdx.x;
  const float* C = cov + (size_t)z * CH * CH;
  float mx = 0.f;
  for(int r = threadIdx.x; r < CH; r += 256){
    float s = 0.f;
    for(int c2 = 0; c2 < CH; ++c2) s += fabsf(C[(size_t)r * CH + c2]);
    mx = fmaxf(mx, s);
  }
  __shared__ float red[256];
  red[threadIdx.x] = mx; __syncthreads();
  for(int w = 128; w > 0; w >>= 1){
    if(threadIdx.x < w) red[threadIdx.x] = fmaxf(red[threadIdx.x], red[threadIdx.x + w]);
    __syncthreads();
  }
  if(threadIdx.x == 0){
    float c = red[0];
    scales[z*4+0] = c;
    scales[z*4+1] = 1.0f / c;
    scales[z*4+2] = sqrtf(c);
    scales[z*4+3] = rsqrtf(c);
  }
}

// ---------------- per-(matrix,channel) mean over 4096 pixels ----------------
__global__ __launch_bounds__(256)
void mean_kernel(const float* __restrict__ content, const float* __restrict__ style,
                 float* __restrict__ meanv){
  int mm = blockIdx.x;           // 0..2047
  int z = mm >> 9, c = mm & 511;
  const float* X = ((z < 2) ? content + (size_t)z * CH * NPIX
                            : style   + (size_t)(z - 2) * CH * NPIX) + (size_t)c * NPIX;
  float s = 0.f;
  for(int i = threadIdx.x; i < NPIX; i += 256) s += X[i];
  __shared__ float red[256];
  red[threadIdx.x] = s; __syncthreads();
  for(int w = 128; w > 0; w >>= 1){
    if(threadIdx.x < w) red[threadIdx.x] += red[threadIdx.x + w];
    __syncthreads();
  }
  if(threadIdx.x == 0) meanv[mm] = red[0] * (1.0f / NPIX);
}

// ------- center + bf16x3 split, emit both [c][pix] and [pix][c] layouts -----
__global__ __launch_bounds__(256)
void center_split_kernel(const float* __restrict__ content, const float* __restrict__ style,
                         const float* __restrict__ meanv,
                         u16* __restrict__ Xch, u16* __restrict__ Xcm, u16* __restrict__ Xcl,
                         u16* __restrict__ XcTh, u16* __restrict__ XcTm, u16* __restrict__ XcTl){
  int z = blockIdx.z;
  const float* X = (z < 2) ? content + (size_t)z * CH * NPIX
                           : style   + (size_t)(z - 2) * CH * NPIX;
  int p0 = blockIdx.x * 64, c0 = blockIdx.y * 64;
  __shared__ float T[64][65];
  int col = threadIdx.x & 63, rq = threadIdx.x >> 6;
#pragma unroll
  for(int i = 0; i < 16; ++i){
    int r = i*4 + rq;
    int c = c0 + r;
    float v = X[(size_t)c * NPIX + p0 + col] - meanv[z*CH + c];
    u16 h, m, l; split3(v, h, m, l);
    size_t o = (size_t)(z*CH + c) * NPIX + p0 + col;
    Xch[o] = h; Xcm[o] = m; Xcl[o] = l;
    T[col][r] = v;
  }
  __syncthreads();
#pragma unroll
  for(int i = 0; i < 16; ++i){
    int r = i*4 + rq;                 // pixel-in-tile
    float v = T[r][col];
    u16 h, m, l; split3(v, h, m, l);
    size_t o = (size_t)(z*NPIX + p0 + r) * CH + c0 + col;
    XcTh[o] = h; XcTm[o] = m; XcTl[o] = l;
  }
}

// ---------------- Y0 = cov/c (x3), Z0 = I (x3) ------------------------------
__global__ __launch_bounds__(256)
void ns_init_kernel(const float* __restrict__ cov, const float* __restrict__ scales,
                    u16* Yh, u16* Ym, u16* Yl, u16* Zh, u16* Zm, u16* Zl){
  size_t t = (size_t)blockIdx.x * 256 + threadIdx.x;   // 4*512*512
  int z = (int)(t >> 18);
  size_t e = t & 262143;
  int row = (int)(e >> 9), col = (int)(e & 511);
  float v = cov[t] * scales[z*4+1];
  u16 h, m, l; split3(v, h, m, l);
  Yh[t] = h; Ym[t] = m; Yl[t] = l;
  Zh[t] = (row == col) ? (u16)0x3F80 : (u16)0;
  Zm[t] = 0; Zl[t] = 0;
}

// ---------------- cn2[p'] = ||whitened style column||^2 ---------------------
__global__ __launch_bounds__(256)
void cn2_kernel(const u16* __restrict__ Wh, const u16* __restrict__ Wm,
                const u16* __restrict__ Wl, float* __restrict__ cn2){
  int b = blockIdx.y;
  int row = blockIdx.x * 16 + (threadIdx.x >> 4);
  int t = threadIdx.x & 15;
  float s = 0.f;
  if(row < PPAD){
    size_t base = ((size_t)(2 + b) * MROWS + row) * CH;
    for(int ch = t; ch < 64; ch += 16){
      uint4 hv = *(const uint4*)(Wh + base + ch*8);
      uint4 mv = *(const uint4*)(Wm + base + ch*8);
      uint4 lv = *(const uint4*)(Wl + base + ch*8);
      const unsigned* hw = (const unsigned*)&hv;
      const unsigned* mw = (const unsigned*)&mv;
      const unsigned* lw = (const unsigned*)&lv;
#pragma unroll
      for(int w = 0; w < 4; ++w){
        float v0 = bf2f((u16)(hw[w] & 0xFFFF)) + bf2f((u16)(mw[w] & 0xFFFF)) + bf2f((u16)(lw[w] & 0xFFFF));
        float v1 = bf2f((u16)(hw[w] >> 16))    + bf2f((u16)(mw[w] >> 16))    + bf2f((u16)(lw[w] >> 16));
        s = fmaf(v0, v0, s); s = fmaf(v1, v1, s);
      }
    }
  }
  for(int off = 8; off; off >>= 1) s += __shfl_down(s, off, 16);
  if(t == 0 && row < PPAD) cn2[b*PPAD + row] = s;
}

// ---------------- rnorm[p] = 1/(sqrt(sum of 9 taps)+1e-5) -------------------
__global__ __launch_bounds__(256)
void rnorm_kernel(const float* __restrict__ cn2, float* __restrict__ rnorm){
  int b = blockIdx.y;
  int p = blockIdx.x * 256 + threadIdx.x;   // 0..4095
  int py = p >> 6, px = p & 63;
  const float* c2 = cn2 + (size_t)b * PPAD + (size_t)py * HPAD + px;
  float s = 0.f;
#pragma unroll
  for(int i = 0; i < 3; ++i)
#pragma unroll
    for(int j = 0; j < 3; ++j) s += c2[i * HPAD + j];
  rnorm[b * 4096 + p] = 1.0f / (sqrtf(s) + 1e-5f);
}

// ---------------- per-p-chunk argmax of 9-tap stencil score (banded) --------
__global__ __launch_bounds__(256)
void score_partial_kernel(const float* __restrict__ S0T, const float* __restrict__ rnorm,
                          float* __restrict__ pmax, int* __restrict__ pidx,
                          int b, int qy0, int colbase){
  int q = qy0*64 + blockIdx.y * 256 + threadIdx.x;
  int chunk = blockIdx.x;
  int qy = q >> 6, qx = q & 63;
  int qcol = qy * HPAD + qx - colbase;
  const float* rn = rnorm + b * 4096;
  float best = -1e30f; int bestp = 0;
  for(int p = chunk * 64; p < chunk * 64 + 64; ++p){
    int py = p >> 6, px = p & 63;
    const float* base = S0T + (size_t)(py * HPAD + px) * BANDW + qcol;
    float s = 0.f;
#pragma unroll
    for(int i = 0; i < 3; ++i)
#pragma unroll
      for(int j = 0; j < 3; ++j)
        s += base[(size_t)(i * HPAD + j) * (BANDW + 1)];
    s *= rn[p];
    if(s > best){ best = s; bestp = p; }
  }
  pmax[(size_t)chunk * 4096 + q] = best;
  pidx[(size_t)chunk * 4096 + q] = bestp;
}

__global__ __launch_bounds__(256)
void argmax_merge_kernel(const float* __restrict__ pmax, const int* __restrict__ pidx,
                         int* __restrict__ idx, int b){
  int q = blockIdx.x * 256 + threadIdx.x;
  float best = -1e30f; int bp = 0;
  for(int ch = 0; ch < 64; ++ch){
    float v = pmax[(size_t)ch * 4096 + q];
    if(v > best){ best = v; bp = pidx[(size_t)ch * 4096 + q]; }
  }
  idx[b * 4096 + q] = bp;
}

// ---------------- gather matched patches, overlap-add, write RT x3 ----------
__global__ __launch_bounds__(256)
void gather_kernel(const u16* __restrict__ Wh, const u16* __restrict__ Wm,
                   const u16* __restrict__ Wl, const int* __restrict__ idx,
                   u16* __restrict__ RTh, u16* __restrict__ RTm, u16* __restrict__ RTl){
  int g = blockIdx.x * 256 + threadIdx.x;   // 2*4096*64
  int cg = g & 63;
  int pix = (g >> 6) & 4095;
  int b = g >> 18;
  int y = pix >> 6, x = pix & 63;
  const int* idxb = idx + b * 4096;
  size_t matbase = (size_t)(2 + b) * MROWS * CH;
  float a8[8] = {0,0,0,0,0,0,0,0};
  int cnt = 0;
#pragma unroll
  for(int i = 0; i < 3; ++i){
    int qy = y + 1 - i;
    if((unsigned)qy >= 64u) continue;
#pragma unroll
    for(int j = 0; j < 3; ++j){
      int qx = x + 1 - j;
      if((unsigned)qx >= 64u) continue;
      int p = idxb[qy * 64 + qx];
      int row = ((p >> 6) + i) * HPAD + (p & 63) + j;
      size_t off = matbase + (size_t)row * CH + cg * 8;
      uint4 hv = *(const uint4*)(Wh + off);
      uint4 mv = *(const uint4*)(Wm + off);
      uint4 lv = *(const uint4*)(Wl + off);
      const unsigned* hw = (const unsigned*)&hv;
      const unsigned* mw = (const unsigned*)&mv;
      const unsigned* lw = (const unsigned*)&lv;
#pragma unroll
      for(int w = 0; w < 4; ++w){
        a8[2*w]   += bf2f((u16)(hw[w] & 0xFFFF)) + bf2f((u16)(mw[w] & 0xFFFF)) + bf2f((u16)(lw[w] & 0xFFFF));
        a8[2*w+1] += bf2f((u16)(hw[w] >> 16))    + bf2f((u16)(mw[w] >> 16))    + bf2f((u16)(lw[w] >> 16));
      }
      ++cnt;
    }
  }
  float inv = 1.0f / (float)cnt;
  u16 oh[8], om[8], ol[8];
#pragma unroll
  for(int k = 0; k < 8; ++k){
    float v = a8[k] * inv;
    split3(v, oh[k], om[k], ol[k]);
  }
  size_t ro = ((size_t)(b * 4096 + pix)) * CH + cg * 8;
  *(uint4*)(RTh + ro) = *(const uint4*)oh;
  *(uint4*)(RTm + ro) = *(const uint4*)om;
  *(uint4*)(RTl + ro) = *(const uint4*)ol;
}

// ---------------------------------------------------------------------------
extern "C" void kernel_launch(void* const* d_in, const int* in_sizes, int n_in,
                              void* d_out, int out_size, void* d_ws, size_t ws_size,
                              hipStream_t stream){
  (void)in_sizes; (void)n_in; (void)out_size; (void)ws_size;
  const float* content = (const float*)d_in[0];
  const float* style   = (const float*)d_in[1];
  float* out = (float*)d_out;

  char* base = (char*)d_ws;
  size_t off = 0;
  auto take = [&](size_t nbytes) -> char* {
    char* p = base + off;
    off = (off + nbytes + 255) & ~(size_t)255;
    return p;
  };
  const size_t MAT = (size_t)CH*CH*2;            // 512x512 bf16 bytes
  const size_t FEAT = (size_t)CH*NPIX*2;         // 512x4096 bf16 bytes
  const size_t WMAT = (size_t)MROWS*CH*2;        // 4480x512 bf16 bytes

  float* meanv  = (float*)take((size_t)4*CH*sizeof(float));
  float* scales = (float*)take(256);
  float* cov    = (float*)take((size_t)4*CH*CH*sizeof(float));
  u16 *Yh=(u16*)take(4*MAT), *Ym=(u16*)take(4*MAT), *Yl=(u16*)take(4*MAT);
  u16 *Zh=(u16*)take(4*MAT), *Zm=(u16*)take(4*MAT), *Zl=(u16*)take(4*MAT);
  u16 *Th=(u16*)take(4*MAT), *Tm=(u16*)take(4*MAT), *Tl=(u16*)take(4*MAT);
  u16 *Ynh=(u16*)take(4*MAT), *Ynm=(u16*)take(4*MAT), *Ynl=(u16*)take(4*MAT);
  u16 *Znh=(u16*)take(4*MAT), *Znm=(u16*)take(4*MAT), *Znl=(u16*)take(4*MAT);
  // cov K-split partials (16 MB) alias the NS temp region (dead at cov time)
  float* covp = (float*)Th;
  // P1: Xc x3 (center->cov)  then  W x3 (post-NS -> end)
  char* P1 = take(3*(size_t)4*WMAT);
  u16 *Xch=(u16*)P1, *Xcm=(u16*)(P1+4*FEAT), *Xcl=(u16*)(P1+8*FEAT);
  u16 *Wh=(u16*)P1, *Wm=(u16*)(P1+4*WMAT), *Wl=(u16*)(P1+8*WMAT);
  // P0: XcT x3 (center->whiten), then S0T band, then RT x3
  char* P0 = take(3*(size_t)4*FEAT);
  u16 *XcTh=(u16*)P0, *XcTm=(u16*)(P0+4*FEAT), *XcTl=(u16*)(P0+8*FEAT);
  float* S0T = (float*)P0;
  u16 *RTh=(u16*)P0, *RTm=(u16*)(P0+2*FEAT), *RTl=(u16*)(P0+4*FEAT);
  float* cn2    = (float*)take((size_t)2*PPAD*sizeof(float));
  float* rnormb = (float*)take((size_t)2*4096*sizeof(float));
  float* pmax   = (float*)take((size_t)64*4096*sizeof(float));
  int*   pidx   = (int*)  take((size_t)64*4096*sizeof(int));
  int*   idxb   = (int*)  take((size_t)2*4096*sizeof(int));

  mean_kernel<<<2048, 256, 0, stream>>>(content, style, meanv);
  center_split_kernel<<<dim3(64, 8, 4), 256, 0, stream>>>(content, style, meanv,
                                                          Xch, Xcm, Xcl, XcTh, XcTm, XcTl);
  // cov partials: z = matrix*4 + K-chunk, 1024 blocks
  {
    GP g{}; g.Ah=Xch; g.Am=Xcm; g.Al=Xcl; g.Bh=Xch; g.Bm=Xcm; g.Bl=Xcl;
    g.sAz = g.sBz = (size_t)CH*NPIX; g.Cf = covp; g.sCz = (size_t)CH*CH;
    g.K = NPIX; g.Kit = 1024;
    gemm_sp<64, M_COVP><<<dim3(8, 8, 16), 256, 0, stream>>>(g);
  }
  cov_reduce_kernel<<<4096, 256, 0, stream>>>(covp, cov);
  scale_kernel<<<4, 256, 0, stream>>>(cov, scales);
  ns_init_kernel<<<4096, 256, 0, stream>>>(cov, scales, Yh, Ym, Yl, Zh, Zm, Zl);

  u16 *Ach[3]={Yh,Ym,Yl}, *Bch[3]={Zh,Zm,Zl}, *An[3]={Ynh,Ynm,Ynl}, *Bn[3]={Znh,Znm,Znl};
  for(int it = 0; it < NS_ITERS; ++it){
    // T = 1.5I - 0.5 Z*Y  (symmetric: 36 triangle blocks, mirrored)
    GP t{}; t.Ah=Bch[0]; t.Am=Bch[1]; t.Al=Bch[2];            // Z
    t.Bh=Ach[0]; t.Bm=Ach[1]; t.Bl=Ach[2];                    // Y (symmetric)
    t.sAz = t.sBz = (size_t)CH*CH; t.Ch=Th; t.Cm=Tm; t.Cl=Tl; t.sCz=(size_t)CH*CH;
    t.K = CH; t.Kit = CH;
    gemm_sp<64, M_NST><<<dim3(36, 1, 4), 256, 0, stream>>>(t);
    // z<4: Yn = Y*T ; z>=4: Zn = T*Z  (both symmetric, mirrored)
    GP u{}; u.Ah=Ach[0]; u.Am=Ach[1]; u.Al=Ach[2];            // Y
    u.Bh=Th; u.Bm=Tm; u.Bl=Tl;                                // T
    u.Eh=Th; u.Em=Tm; u.El=Tl;                                // T
    u.Fh=Bch[0]; u.Fm=Bch[1]; u.Fl=Bch[2];                    // Z
    u.Ch=An[0]; u.Cm=An[1]; u.Cl=An[2];
    u.Gh=Bn[0]; u.Gm=Bn[1]; u.Gl=Bn[2];
    u.sCz=(size_t)CH*CH; u.K = CH; u.Kit = CH;
    gemm_sp<64, M_X3><<<dim3(36, 1, 8), 256, 0, stream>>>(u);
    for(int c = 0; c < 3; ++c){ u16* tmp=Ach[c]; Ach[c]=An[c]; An[c]=tmp;
                                tmp=Bch[c]; Bch[c]=Bn[c]; Bn[c]=tmp; }
  }

  // W (padded, zero borders) -- Xc region is dead now; Wh/Wm/Wl alias it
  hipMemsetAsync(Wh, 0, 4*WMAT, stream);
  hipMemsetAsync(Wm, 0, 4*WMAT, stream);
  hipMemsetAsync(Wl, 0, 4*WMAT, stream);
  // W[pix][c] = XcT * Z  (Z symmetric), scaled by rsqrt(c)
  {
    GP w{}; w.Ah=XcTh; w.Am=XcTm; w.Al=XcTl; w.sAz=(size_t)NPIX*CH;
    w.Bh=Bch[0]; w.Bm=Bch[1]; w.Bl=Bch[2]; w.sBz=(size_t)CH*CH;
    w.Ch=Wh; w.Cm=Wm; w.Cl=Wl; w.sCz=(size_t)MROWS*CH; w.scales=scales;
    w.K = CH; w.Kit = CH;
    gemm_sp<128, M_WHITEN><<<dim3(4, 32, 4), 256, 0, stream>>>(w);
  }
  cn2_kernel<<<dim3(273, 2), 256, 0, stream>>>(Wh, Wm, Wl, cn2);
  rnorm_kernel<<<dim3(16, 2), 256, 0, stream>>>(cn2, rnormb);

  for(int b = 0; b < 2; ++b){
    for(int band = 0; band < 2; ++band){
      GP s{};
      s.Ah = Wh + (size_t)(2+b)*MROWS*CH; s.Am = Wm + (size_t)(2+b)*MROWS*CH; s.Al = Wl + (size_t)(2+b)*MROWS*CH;
      size_t bo = (size_t)b*MROWS*CH + (size_t)(band ? BANDOFF : 0)*CH;
      s.Bh = Wh + bo; s.Bm = Wm + bo; s.Bl = Wl + bo;
      s.sAz = s.sBz = 0; s.Cf = S0T; s.sCz = 0; s.K = CH; s.Kit = CH;
      gemm_sp<128, M_S0><<<dim3(BANDW/128, MROWS/128, 1), 256, 0, stream>>>(s);
      score_partial_kernel<<<dim3(64, 8), 256, 0, stream>>>(S0T, rnormb, pmax, pidx,
                                                            b, band ? 32 : 0,
                                                            band ? BANDOFF : 0);
    }
    argmax_merge_kernel<<<16, 256, 0, stream>>>(pmax, pidx, idxb, b);
  }

  gather_kernel<<<2048, 256, 0, stream>>>(Wh, Wm, Wl, idxb, RTh, RTm, RTl);
  // out = Ys * R * sqrt(c) + mu   (Ys symmetric)
  {
    GP c{}; c.Ah = Ach[0] + 2*(size_t)CH*CH; c.Am = Ach[1] + 2*(size_t)CH*CH; c.Al = Ach[2] + 2*(size_t)CH*CH;
    c.sAz = (size_t)CH*CH;
    c.Bh = RTh; c.Bm = RTm; c.Bl = RTl; c.sBz = (size_t)NPIX*CH;
    c.Cf = out; c.sCz = (size_t)CH*NPIX; c.scales = scales; c.meanv = meanv;
    c.K = CH; c.Kit = CH;
    gemm_sp<128, M_COLOR><<<dim3(32, 4, 2), 256, 0, stream>>>(c);
  }
}

// Round 6
// 962.240 us; speedup vs baseline: 1.7004x; 1.4292x over previous
//
#include <hip/hip_runtime.h>

// ---------------------------------------------------------------------------
// StyleDecorator, round 6: scaled fp16x2 split (3-product, dual accumulator)
// replaces bf16x3 (6-product) in every GEMM: h=fp16(x), l2=fp16((x-h)*2^11),
// v = acc_hh + acc_cross * 2^-11. Error ~3*2^-24 (fp32-grade), no denormals.
// 2/3 staging bytes, 1/2 MFMA work vs round 5.
//  - NS 9 iters (scalar map converges to 1-5e-12 in 8 from s0=0.056).
//  - scale via parallel column-abs-sum (symmetric cov) + atomicMax on bits.
// ---------------------------------------------------------------------------

#define CH    512
#define NPIX  4096      // 64*64
#define HPAD  66
#define PPAD  4356      // 66*66
#define MROWS 4480      // padded row count for whitened-feature matrices
#define BANDW 2304      // S0T column band width (two bands cover 4416 cols)
#define BANDOFF 2112    // second band column offset
#define NS_ITERS 9

typedef unsigned short u16;
typedef _Float16 half8 __attribute__((ext_vector_type(8)));
typedef __attribute__((ext_vector_type(4))) float f32x4;    // MFMA C/D

__device__ __forceinline__ float f16tof(u16 h){
  union { u16 u; _Float16 f; } v; v.u = h; return (float)v.f;
}
__device__ __forceinline__ u16 ftof16(float x){
  union { u16 u; _Float16 f; } v; v.f = (_Float16)x; return v.u;
}
// x ~= h + l*2^-11, with l ~ 0.5|x| (never denormal). err ~ 2^-24|x|.
__device__ __forceinline__ void split2(float x, u16& h, u16& l){
  _Float16 hf = (_Float16)x;
  float r = (x - (float)hf) * 2048.0f;
  union { u16 u; _Float16 f; } hv, lv;
  hv.f = hf; lv.f = (_Float16)r;
  h = hv.u; l = lv.u;
}
__device__ __forceinline__ void gll16(const void* g, void* l){
  __builtin_amdgcn_global_load_lds((const __attribute__((address_space(1))) unsigned*)g,
                                   (__attribute__((address_space(3))) unsigned*)l,
                                   16, 0, 0);
}
__device__ __forceinline__ f32x4 mfma_f16(half8 a, half8 b, f32x4 c){
  return __builtin_amdgcn_mfma_f32_16x16x32_f16(a, b, c, 0, 0, 0);
}

// ---------------------------------------------------------------------------
enum { M_COVP = 0, M_NST = 1, M_X3 = 2, M_WHITEN = 3, M_S0 = 4, M_COLOR = 5 };

struct GP {
  const u16 *Ah, *Al, *Bh, *Bl;
  const u16 *Eh, *El, *Fh, *Fl;   // alt A/B for M_X3 z>=4
  size_t sAz, sBz;           // per-z strides (elements)
  float* Cf;
  u16 *Ch, *Cl;
  u16 *Gh, *Gl;              // alt C for M_X3 z>=4
  size_t sCz;
  const float* scales;
  const float* meanv;
  int K;                     // row stride (elements)
  int Kit;                   // K iteration length for this launch
};

// C[m][n] = sum_k A[m][k]*B[n][k], A,B as [row][K] fp16x2 (h, l*2^11).
// 256 threads = 4 waves; TILE in {64,128}; wave computes (TILE/2)^2.
template<int TILE, int MODE>
__global__ __launch_bounds__(256, 2)
void gemm_sp(GP p){
  constexpr int MF = TILE / 32;
  constexpr bool SYM = (MODE == M_NST) || (MODE == M_X3);
  const int z = blockIdx.z;
  int m0, n0;
  int kbase = 0;
  bool mirror = false;
  if constexpr (MODE == M_COVP){
    m0 = blockIdx.y*64; n0 = blockIdx.x*64;
    kbase = (z & 3) * p.Kit;
  } else if constexpr (SYM){
    int bx = blockIdx.x;
    int ty = (int)((sqrtf(8.f*bx + 1.f) - 1.f)*0.5f);
    while((ty+1)*(ty+2)/2 <= bx) ++ty;
    while(ty*(ty+1)/2 > bx) --ty;
    int tx = bx - ty*(ty+1)/2;
    m0 = ty*64; n0 = tx*64; mirror = (tx != ty);
  } else if constexpr (MODE == M_S0){
    const int lin = blockIdx.y*18 + blockIdx.x;
    const int mg = lin/90, r = lin%90;
    m0 = (mg*5 + (r%5))*128; n0 = (r/5)*128;
  } else {
    m0 = blockIdx.y*TILE; n0 = blockIdx.x*TILE;
  }

  const u16 *Ah, *Al, *Bh, *Bl;
  if constexpr (MODE == M_X3){
    const size_t zb = (size_t)(z & 3) * CH * CH;
    if(z < 4){ Ah=p.Ah+zb; Al=p.Al+zb; Bh=p.Bh+zb; Bl=p.Bl+zb; }
    else     { Ah=p.Eh+zb; Al=p.El+zb; Bh=p.Fh+zb; Bl=p.Fl+zb; }
  } else {
    const int za = (MODE == M_COVP) ? (z >> 2) : z;
    Ah = p.Ah + (size_t)za * p.sAz;
    Al = p.Al + (size_t)za * p.sAz;
    Bh = p.Bh + (size_t)za * p.sBz;
    Bl = p.Bl + (size_t)za * p.sBz;
  }

  const int tid = threadIdx.x, ln = tid & 63, wv = tid >> 6;
  const int wm = (wv >> 1) * (TILE/2), wn = (wv & 1) * (TILE/2);
  __shared__ __align__(16) u16 sAh[TILE*32], sAl[TILE*32];
  __shared__ __align__(16) u16 sBh[TILE*32], sBl[TILE*32];
  f32x4 acc1[MF][MF], acc2[MF][MF];
#pragma unroll
  for(int i=0;i<MF;++i)
#pragma unroll
    for(int j=0;j<MF;++j){ acc1[i][j] = (f32x4)0.0f; acc2[i][j] = (f32x4)0.0f; }
  const int K = p.K;
  for(int kk = 0; kk < p.Kit; kk += 32){
    const int k0 = kbase + kk;
#pragma unroll
    for(int s = tid; s < TILE*4; s += 256){      // 16B slots, 4 per row
      const int row = s >> 2, pos = s & 3;
      const int kc = pos ^ ((row >> 2) & 3);     // XOR swizzle
      const size_t ga = (size_t)(m0 + row) * K + k0 + kc*8;
      const size_t gb = (size_t)(n0 + row) * K + k0 + kc*8;
      gll16(Ah + ga, sAh + s*8);
      gll16(Al + ga, sAl + s*8);
      gll16(Bh + gb, sBh + s*8);
      gll16(Bl + gb, sBl + s*8);
    }
    __syncthreads();
    half8 ah[MF], al[MF], bh[MF], bl[MF];
#pragma unroll
    for(int i=0;i<MF;++i){
      const int ra = wm + i*16 + (ln & 15);
      const int rb = wn + i*16 + (ln & 15);
      const int pa = (ln >> 4) ^ ((ra >> 2) & 3);
      const int pb = (ln >> 4) ^ ((rb >> 2) & 3);
      const int ofa = ra*32 + pa*8;
      const int ofb = rb*32 + pb*8;
      ah[i] = *(const half8*)(sAh + ofa);
      al[i] = *(const half8*)(sAl + ofa);
      bh[i] = *(const half8*)(sBh + ofb);
      bl[i] = *(const half8*)(sBl + ofb);
    }
#pragma unroll
    for(int i=0;i<MF;++i)
#pragma unroll
      for(int j=0;j<MF;++j){
        acc1[i][j] = mfma_f16(ah[i], bh[j], acc1[i][j]);
        acc2[i][j] = mfma_f16(ah[i], bl[j], acc2[i][j]);
        acc2[i][j] = mfma_f16(al[i], bh[j], acc2[i][j]);
      }
    __syncthreads();
  }
  // epilogue: C/D layout col=lane&15, row=(lane>>4)*4+reg
  u16 *C0 = nullptr, *C1 = nullptr;
  if constexpr (MODE == M_NST){
    const size_t zb = (size_t)z * p.sCz;
    C0 = p.Ch + zb; C1 = p.Cl + zb;
  } else if constexpr (MODE == M_X3){
    const size_t zb = (size_t)(z & 3) * p.sCz;
    if(z < 4){ C0 = p.Ch + zb; C1 = p.Cl + zb; }
    else     { C0 = p.Gh + zb; C1 = p.Gl + zb; }
  }
#pragma unroll
  for(int i=0;i<MF;++i)
#pragma unroll
    for(int j=0;j<MF;++j)
#pragma unroll
      for(int r=0;r<4;++r){
        const int m = m0 + wm + i*16 + (ln >> 4)*4 + r;
        const int n = n0 + wn + j*16 + (ln & 15);
        float v = acc1[i][j][r] + acc2[i][j][r] * (1.0f/2048.0f);
        if constexpr (MODE == M_COVP){
          p.Cf[(size_t)z * p.sCz + (size_t)m * CH + n] = v;   // raw partial
        } else if constexpr (MODE == M_NST || MODE == M_X3){
          if constexpr (MODE == M_NST) v = -0.5f*v + ((m == n) ? 1.5f : 0.0f);
          u16 h, l; split2(v, h, l);
          C0[(size_t)m*CH + n] = h; C1[(size_t)m*CH + n] = l;
          if(mirror){
            C0[(size_t)n*CH + m] = h; C1[(size_t)n*CH + m] = l;
          }
        } else if constexpr (MODE == M_WHITEN){
          v *= p.scales[z*4 + 3];                 // rsqrt(c)
          const int prow = ((m >> 6) + 1)*HPAD + (m & 63) + 1;
          u16 h, l; split2(v, h, l);
          const size_t o = (size_t)z*p.sCz + (size_t)prow*CH + n;
          p.Ch[o] = h; p.Cl[o] = l;
        } else if constexpr (MODE == M_S0){
          p.Cf[(size_t)m * BANDW + n] = v;
        } else {                                  // M_COLOR
          const float sc = p.scales[(2+z)*4 + 2]; // sqrt(c)
          const float mu = p.meanv[(2+z)*CH + m];
          p.Cf[(size_t)z*p.sCz + (size_t)m*NPIX + n] = v*sc + mu;
        }
      }
}

// ---------------- cov reduce: sum 4 K-chunks, scale 1/4095 ------------------
__global__ __launch_bounds__(256)
void cov_reduce_kernel(const float* __restrict__ covp, float* __restrict__ cov){
  size_t t = (size_t)blockIdx.x * 256 + threadIdx.x;   // 4*512*512
  int z = (int)(t >> 18);
  size_t e = t & 262143;
  float s = 0.f;
#pragma unroll
  for(int c = 0; c < 4; ++c) s += covp[((size_t)(z*4 + c) << 18) + e];
  cov[t] = s * (1.0f / 4095.0f);
}

// ---- scale: ||A||_inf via column abs-sums (A symmetric -> coalesced) -------
// cmax starts as 0xAAAAAAAA (poisoned ws) = negative int: any pos float wins.
__global__ __launch_bounds__(256)
void scale_pre_kernel(const float* __restrict__ cov, int* __restrict__ cmax){
  const int z = blockIdx.y;
  const int col = blockIdx.x * 256 + threadIdx.x;
  const float* C = cov + (size_t)z * CH * CH;
  float s = 0.f;
  for(int r = 0; r < CH; ++r) s += fabsf(C[(size_t)r * CH + col]);
  atomicMax(&cmax[z], __float_as_int(s));
}
__global__ __launch_bounds__(64)
void scale_fin_kernel(const int* __restrict__ cmax, float* __restrict__ scales){
  int z = threadIdx.x;
  if(z < 4){
    float c = __int_as_float(cmax[z]);
    scales[z*4+0] = c;
    scales[z*4+1] = 1.0f / c;
    scales[z*4+2] = sqrtf(c);
    scales[z*4+3] = rsqrtf(c);
  }
}

// ---------------- per-(matrix,channel) mean over 4096 pixels ----------------
__global__ __launch_bounds__(256)
void mean_kernel(const float* __restrict__ content, const float* __restrict__ style,
                 float* __restrict__ meanv){
  int mm = blockIdx.x;           // 0..2047
  int z = mm >> 9, c = mm & 511;
  const float* X = ((z < 2) ? content + (size_t)z * CH * NPIX
                            : style   + (size_t)(z - 2) * CH * NPIX) + (size_t)c * NPIX;
  float s = 0.f;
  for(int i = threadIdx.x; i < NPIX; i += 256) s += X[i];
  __shared__ float red[256];
  red[threadIdx.x] = s; __syncthreads();
  for(int w = 128; w > 0; w >>= 1){
    if(threadIdx.x < w) red[threadIdx.x] += red[threadIdx.x + w];
    __syncthreads();
  }
  if(threadIdx.x == 0) meanv[mm] = red[0] * (1.0f / NPIX);
}

// ------- center + fp16x2 split, emit both [c][pix] and [pix][c] layouts -----
__global__ __launch_bounds__(256)
void center_split_kernel(const float* __restrict__ content, const float* __restrict__ style,
                         const float* __restrict__ meanv,
                         u16* __restrict__ Xch, u16* __restrict__ Xcl,
                         u16* __restrict__ XcTh, u16* __restrict__ XcTl){
  int z = blockIdx.z;
  const float* X = (z < 2) ? content + (size_t)z * CH * NPIX
                           : style   + (size_t)(z - 2) * CH * NPIX;
  int p0 = blockIdx.x * 64, c0 = blockIdx.y * 64;
  __shared__ float T[64][65];
  int col = threadIdx.x & 63, rq = threadIdx.x >> 6;
#pragma unroll
  for(int i = 0; i < 16; ++i){
    int r = i*4 + rq;
    int c = c0 + r;
    float v = X[(size_t)c * NPIX + p0 + col] - meanv[z*CH + c];
    u16 h, l; split2(v, h, l);
    size_t o = (size_t)(z*CH + c) * NPIX + p0 + col;
    Xch[o] = h; Xcl[o] = l;
    T[col][r] = v;
  }
  __syncthreads();
#pragma unroll
  for(int i = 0; i < 16; ++i){
    int r = i*4 + rq;                 // pixel-in-tile
    float v = T[r][col];
    u16 h, l; split2(v, h, l);
    size_t o = (size_t)(z*NPIX + p0 + r) * CH + c0 + col;
    XcTh[o] = h; XcTl[o] = l;
  }
}

// ---------------- Y0 = cov/c (x2), Z0 = I (x2) ------------------------------
__global__ __launch_bounds__(256)
void ns_init_kernel(const float* __restrict__ cov, const float* __restrict__ scales,
                    u16* Yh, u16* Yl, u16* Zh, u16* Zl){
  size_t t = (size_t)blockIdx.x * 256 + threadIdx.x;   // 4*512*512
  int z = (int)(t >> 18);
  size_t e = t & 262143;
  int row = (int)(e >> 9), col = (int)(e & 511);
  float v = cov[t] * scales[z*4+1];
  u16 h, l; split2(v, h, l);
  Yh[t] = h; Yl[t] = l;
  Zh[t] = (row == col) ? (u16)0x3C00 : (u16)0;   // fp16 1.0
  Zl[t] = 0;
}

// ---------------- cn2[p'] = ||whitened style column||^2 ---------------------
__global__ __launch_bounds__(256)
void cn2_kernel(const u16* __restrict__ Wh, const u16* __restrict__ Wl,
                float* __restrict__ cn2){
  int b = blockIdx.y;
  int row = blockIdx.x * 16 + (threadIdx.x >> 4);
  int t = threadIdx.x & 15;
  float s = 0.f;
  if(row < PPAD){
    size_t base = ((size_t)(2 + b) * MROWS + row) * CH;
    for(int ch = t; ch < 64; ch += 16){
      uint4 hv = *(const uint4*)(Wh + base + ch*8);
      uint4 lv = *(const uint4*)(Wl + base + ch*8);
      const unsigned* hw = (const unsigned*)&hv;
      const unsigned* lw = (const unsigned*)&lv;
#pragma unroll
      for(int w = 0; w < 4; ++w){
        float v0 = f16tof((u16)(hw[w] & 0xFFFF)) + f16tof((u16)(lw[w] & 0xFFFF))*(1.0f/2048.0f);
        float v1 = f16tof((u16)(hw[w] >> 16))    + f16tof((u16)(lw[w] >> 16))*(1.0f/2048.0f);
        s = fmaf(v0, v0, s); s = fmaf(v1, v1, s);
      }
    }
  }
  for(int off = 8; off; off >>= 1) s += __shfl_down(s, off, 16);
  if(t == 0 && row < PPAD) cn2[b*PPAD + row] = s;
}

// ---------------- rnorm[p] = 1/(sqrt(sum of 9 taps)+1e-5) -------------------
__global__ __launch_bounds__(256)
void rnorm_kernel(const float* __restrict__ cn2, float* __restrict__ rnorm){
  int b = blockIdx.y;
  int p = blockIdx.x * 256 + threadIdx.x;   // 0..4095
  int py = p >> 6, px = p & 63;
  const float* c2 = cn2 + (size_t)b * PPAD + (size_t)py * HPAD + px;
  float s = 0.f;
#pragma unroll
  for(int i = 0; i < 3; ++i)
#pragma unroll
    for(int j = 0; j < 3; ++j) s += c2[i * HPAD + j];
  rnorm[b * 4096 + p] = 1.0f / (sqrtf(s) + 1e-5f);
}

// ---------------- per-p-chunk argmax of 9-tap stencil score (banded) --------
__global__ __launch_bounds__(256)
void score_partial_kernel(const float* __restrict__ S0T, const float* __restrict__ rnorm,
                          float* __restrict__ pmax, int* __restrict__ pidx,
                          int b, int qy0, int colbase){
  int q = qy0*64 + blockIdx.y * 256 + threadIdx.x;
  int chunk = blockIdx.x;
  int qy = q >> 6, qx = q & 63;
  int qcol = qy * HPAD + qx - colbase;
  const float* rn = rnorm + b * 4096;
  float best = -1e30f; int bestp = 0;
  for(int p = chunk * 64; p < chunk * 64 + 64; ++p){
    int py = p >> 6, px = p & 63;
    const float* base = S0T + (size_t)(py * HPAD + px) * BANDW + qcol;
    float s = 0.f;
#pragma unroll
    for(int i = 0; i < 3; ++i)
#pragma unroll
      for(int j = 0; j < 3; ++j)
        s += base[(size_t)(i * HPAD + j) * (BANDW + 1)];
    s *= rn[p];
    if(s > best){ best = s; bestp = p; }
  }
  pmax[(size_t)chunk * 4096 + q] = best;
  pidx[(size_t)chunk * 4096 + q] = bestp;
}

__global__ __launch_bounds__(256)
void argmax_merge_kernel(const float* __restrict__ pmax, const int* __restrict__ pidx,
                         int* __restrict__ idx, int b){
  int q = blockIdx.x * 256 + threadIdx.x;
  float best = -1e30f; int bp = 0;
  for(int ch = 0; ch < 64; ++ch){
    float v = pmax[(size_t)ch * 4096 + q];
    if(v > best){ best = v; bp = pidx[(size_t)ch * 4096 + q]; }
  }
  idx[b * 4096 + q] = bp;
}

// ---------------- gather matched patches, overlap-add, write RT x2 ----------
__global__ __launch_bounds__(256)
void gather_kernel(const u16* __restrict__ Wh, const u16* __restrict__ Wl,
                   const int* __restrict__ idx,
                   u16* __restrict__ RTh, u16* __restrict__ RTl){
  int g = blockIdx.x * 256 + threadIdx.x;   // 2*4096*64
  int cg = g & 63;
  int pix = (g >> 6) & 4095;
  int b = g >> 18;
  int y = pix >> 6, x = pix & 63;
  const int* idxb = idx + b * 4096;
  size_t matbase = (size_t)(2 + b) * MROWS * CH;
  float a8[8] = {0,0,0,0,0,0,0,0};
  int cnt = 0;
#pragma unroll
  for(int i = 0; i < 3; ++i){
    int qy = y + 1 - i;
    if((unsigned)qy >= 64u) continue;
#pragma unroll
    for(int j = 0; j < 3; ++j){
      int qx = x + 1 - j;
      if((unsigned)qx >= 64u) continue;
      int p = idxb[qy * 64 + qx];
      int row = ((p >> 6) + i) * HPAD + (p & 63) + j;
      size_t off = matbase + (size_t)row * CH + cg * 8;
      uint4 hv = *(const uint4*)(Wh + off);
      uint4 lv = *(const uint4*)(Wl + off);
      const unsigned* hw = (const unsigned*)&hv;
      const unsigned* lw = (const unsigned*)&lv;
#pragma unroll
      for(int w = 0; w < 4; ++w){
        a8[2*w]   += f16tof((u16)(hw[w] & 0xFFFF)) + f16tof((u16)(lw[w] & 0xFFFF))*(1.0f/2048.0f);
        a8[2*w+1] += f16tof((u16)(hw[w] >> 16))    + f16tof((u16)(lw[w] >> 16))*(1.0f/2048.0f);
      }
      ++cnt;
    }
  }
  float inv = 1.0f / (float)cnt;
  u16 oh[8], ol[8];
#pragma unroll
  for(int k = 0; k < 8; ++k){
    float v = a8[k] * inv;
    split2(v, oh[k], ol[k]);
  }
  size_t ro = ((size_t)(b * 4096 + pix)) * CH + cg * 8;
  *(uint4*)(RTh + ro) = *(const uint4*)oh;
  *(uint4*)(RTl + ro) = *(const uint4*)ol;
}

// ---------------------------------------------------------------------------
extern "C" void kernel_launch(void* const* d_in, const int* in_sizes, int n_in,
                              void* d_out, int out_size, void* d_ws, size_t ws_size,
                              hipStream_t stream){
  (void)in_sizes; (void)n_in; (void)out_size; (void)ws_size;
  const float* content = (const float*)d_in[0];
  const float* style   = (const float*)d_in[1];
  float* out = (float*)d_out;

  char* base = (char*)d_ws;
  size_t off = 0;
  auto take = [&](size_t nbytes) -> char* {
    char* p = base + off;
    off = (off + nbytes + 255) & ~(size_t)255;
    return p;
  };
  const size_t MAT = (size_t)CH*CH*2;            // 512x512 fp16 bytes
  const size_t FEAT = (size_t)CH*NPIX*2;         // 512x4096 fp16 bytes
  const size_t WMAT = (size_t)MROWS*CH*2;        // 4480x512 fp16 bytes
  const size_t S0SZ = (size_t)MROWS*BANDW*4;     // 41.3 MB

  float* meanv  = (float*)take((size_t)4*CH*sizeof(float));
  float* scales = (float*)take(256);
  int*   cmax   = (int*)  take(256);             // poisoned 0xAA.. = negative
  float* cov    = (float*)take((size_t)4*CH*CH*sizeof(float));
  float* covp   = (float*)take((size_t)16*CH*CH*sizeof(float));
  u16 *Yh=(u16*)take(4*MAT), *Yl=(u16*)take(4*MAT);
  u16 *Zh=(u16*)take(4*MAT), *Zl=(u16*)take(4*MAT);
  u16 *Th=(u16*)take(4*MAT), *Tl=(u16*)take(4*MAT);
  u16 *Ynh=(u16*)take(4*MAT), *Ynl=(u16*)take(4*MAT);
  u16 *Znh=(u16*)take(4*MAT), *Znl=(u16*)take(4*MAT);
  // P1: Xc x2 (center->cov) then W x2 (post-NS -> end)
  char* P1 = take(2*(size_t)4*WMAT);
  u16 *Xch=(u16*)P1, *Xcl=(u16*)(P1+4*FEAT);
  u16 *Wh=(u16*)P1,  *Wl=(u16*)(P1+4*WMAT);
  // P0: XcT x2 (center->whiten), then S0T band, then RT x2
  char* P0 = take(S0SZ);                          // >= 2*4*FEAT (33.5MB)
  u16 *XcTh=(u16*)P0, *XcTl=(u16*)(P0+4*FEAT);
  float* S0T = (float*)P0;
  u16 *RTh=(u16*)P0, *RTl=(u16*)(P0+2*FEAT);
  float* cn2    = (float*)take((size_t)2*PPAD*sizeof(float));
  float* rnormb = (float*)take((size_t)2*4096*sizeof(float));
  float* pmax   = (float*)take((size_t)64*4096*sizeof(float));
  int*   pidx   = (int*)  take((size_t)64*4096*sizeof(int));
  int*   idxb   = (int*)  take((size_t)2*4096*sizeof(int));

  mean_kernel<<<2048, 256, 0, stream>>>(content, style, meanv);
  center_split_kernel<<<dim3(64, 8, 4), 256, 0, stream>>>(content, style, meanv,
                                                          Xch, Xcl, XcTh, XcTl);
  // cov partials: z = matrix*4 + K-chunk, 1024 blocks
  {
    GP g{}; g.Ah=Xch; g.Al=Xcl; g.Bh=Xch; g.Bl=Xcl;
    g.sAz = g.sBz = (size_t)CH*NPIX; g.Cf = covp; g.sCz = (size_t)CH*CH;
    g.K = NPIX; g.Kit = 1024;
    gemm_sp<64, M_COVP><<<dim3(8, 8, 16), 256, 0, stream>>>(g);
  }
  cov_reduce_kernel<<<4096, 256, 0, stream>>>(covp, cov);
  scale_pre_kernel<<<dim3(2, 4), 256, 0, stream>>>(cov, cmax);
  scale_fin_kernel<<<1, 64, 0, stream>>>(cmax, scales);
  ns_init_kernel<<<4096, 256, 0, stream>>>(cov, scales, Yh, Yl, Zh, Zl);

  u16 *Ach[2]={Yh,Yl}, *Bch[2]={Zh,Zl}, *An[2]={Ynh,Ynl}, *Bn[2]={Znh,Znl};
  for(int it = 0; it < NS_ITERS; ++it){
    // T = 1.5I - 0.5 Z*Y  (symmetric: 36 triangle blocks, mirrored)
    GP t{}; t.Ah=Bch[0]; t.Al=Bch[1];            // Z
    t.Bh=Ach[0]; t.Bl=Ach[1];                    // Y (symmetric)
    t.sAz = t.sBz = (size_t)CH*CH; t.Ch=Th; t.Cl=Tl; t.sCz=(size_t)CH*CH;
    t.K = CH; t.Kit = CH;
    gemm_sp<64, M_NST><<<dim3(36, 1, 4), 256, 0, stream>>>(t);
    // z<4: Yn = Y*T ; z>=4: Zn = T*Z  (both symmetric, mirrored)
    GP u{}; u.Ah=Ach[0]; u.Al=Ach[1];            // Y
    u.Bh=Th; u.Bl=Tl;                            // T
    u.Eh=Th; u.El=Tl;                            // T
    u.Fh=Bch[0]; u.Fl=Bch[1];                    // Z
    u.Ch=An[0]; u.Cl=An[1];
    u.Gh=Bn[0]; u.Gl=Bn[1];
    u.sCz=(size_t)CH*CH; u.K = CH; u.Kit = CH;
    gemm_sp<64, M_X3><<<dim3(36, 1, 8), 256, 0, stream>>>(u);
    for(int c = 0; c < 2; ++c){ u16* tmp=Ach[c]; Ach[c]=An[c]; An[c]=tmp;
                                tmp=Bch[c]; Bch[c]=Bn[c]; Bn[c]=tmp; }
  }

  // W (padded, zero borders) -- Xc region is dead now; Wh/Wl alias it
  hipMemsetAsync(Wh, 0, 4*WMAT, stream);
  hipMemsetAsync(Wl, 0, 4*WMAT, stream);
  // W[pix][c] = XcT * Z  (Z symmetric), scaled by rsqrt(c)
  {
    GP w{}; w.Ah=XcTh; w.Al=XcTl; w.sAz=(size_t)NPIX*CH;
    w.Bh=Bch[0]; w.Bl=Bch[1]; w.sBz=(size_t)CH*CH;
    w.Ch=Wh; w.Cl=Wl; w.sCz=(size_t)MROWS*CH; w.scales=scales;
    w.K = CH; w.Kit = CH;
    gemm_sp<128, M_WHITEN><<<dim3(4, 32, 4), 256, 0, stream>>>(w);
  }
  cn2_kernel<<<dim3(273, 2), 256, 0, stream>>>(Wh, Wl, cn2);
  rnorm_kernel<<<dim3(16, 2), 256, 0, stream>>>(cn2, rnormb);

  for(int b = 0; b < 2; ++b){
    for(int band = 0; band < 2; ++band){
      GP s{};
      s.Ah = Wh + (size_t)(2+b)*MROWS*CH; s.Al = Wl + (size_t)(2+b)*MROWS*CH;
      size_t bo = (size_t)b*MROWS*CH + (size_t)(band ? BANDOFF : 0)*CH;
      s.Bh = Wh + bo; s.Bl = Wl + bo;
      s.sAz = s.sBz = 0; s.Cf = S0T; s.sCz = 0; s.K = CH; s.Kit = CH;
      gemm_sp<128, M_S0><<<dim3(BANDW/128, MROWS/128, 1), 256, 0, stream>>>(s);
      score_partial_kernel<<<dim3(64, 8), 256, 0, stream>>>(S0T, rnormb, pmax, pidx,
                                                            b, band ? 32 : 0,
                                                            band ? BANDOFF : 0);
    }
    argmax_merge_kernel<<<16, 256, 0, stream>>>(pmax, pidx, idxb, b);
  }

  gather_kernel<<<2048, 256, 0, stream>>>(Wh, Wl, idxb, RTh, RTl);
  // out = Ys * R * sqrt(c) + mu   (Ys symmetric)
  {
    GP c{}; c.Ah = Ach[0] + 2*(size_t)CH*CH; c.Al = Ach[1] + 2*(size_t)CH*CH;
    c.sAz = (size_t)CH*CH;
    c.Bh = RTh; c.Bl = RTl; c.sBz = (size_t)NPIX*CH;
    c.Cf = out; c.sCz = (size_t)CH*NPIX; c.scales = scales; c.meanv = meanv;
    c.K = CH; c.Kit = CH;
    gemm_sp<128, M_COLOR><<<dim3(32, 4, 2), 256, 0, stream>>>(c);
  }
}